// Round 6
// baseline (4417.300 us; speedup 1.0000x reference)
//
#include <hip/hip_runtime.h>

#define SEQ  4096
#define HID  128
#define BT   8            // 8 batch cols per block = 2 instances x 4 cols
#define NBLK (256 / BT)   // 32 blocks

typedef _Float16 half8 __attribute__((ext_vector_type(8)));
typedef _Float16 half4 __attribute__((ext_vector_type(4)));
typedef float    f32x4 __attribute__((ext_vector_type(4)));

#define L2E  1.44269504088896340736f   // log2(e)
#define L2E2 2.88539008177792681472f   // 2*log2(e)

__device__ __forceinline__ float exp2_(float x) { return __builtin_amdgcn_exp2f(x); }
__device__ __forceinline__ float rcp_(float x)  { return __builtin_amdgcn_rcpf(x); }
// gate pre-scaled by log2e: sigmoid(x) = 1/(1+2^-x')
__device__ __forceinline__ float sigm2(float xp) { return rcp_(1.f + exp2_(-xp)); }
// gate pre-scaled by 2*log2e: tanh(x) = 1 - 2/(1+2^x')
__device__ __forceinline__ float tanh2(float xp) { return 1.f - 2.f * rcp_(1.f + exp2_(xp)); }

// Two independent 4-col LSTM instances per block, software-pipelined inside the
// same waves: instance B's issue stream hides instance A's ds_read/MFMA/TRANS
// latency (and vice versa). One barrier per step covers both instances.
// Wave w owns gate M-tiles {w,w+8,w+16,w+24}; B operand replicated over the 4
// column groups (col = n&3) so the epilogue is lane-local (proven rounds 4-5).
__global__ __launch_bounds__(512, 2)
void lstm_mfma(const float* __restrict__ inputs,   // (B,S,3)
               const float* __restrict__ hx0,      // (B,128)
               const float* __restrict__ cx0,      // (B,128)
               const float* __restrict__ W_inp,    // (64,3)
               const float* __restrict__ b_inp,    // (64)
               const float* __restrict__ W_ih,     // (512,64)
               const float* __restrict__ b_ih,     // (512)
               const float* __restrict__ W_hh,     // (512,128)
               const float* __restrict__ b_hh,     // (512)
               const float* __restrict__ W_out,    // (40,128)
               const float* __restrict__ b_out,    // (40)
               float*       __restrict__ out)      // (B,40)
{
    // per-instance h state, double-buffered, transposed:
    // element (kt,q,c,i) = h[k = kt*32 + q*8 + i][col c]
    __shared__ _Float16 xvA[2][4][4][4][8];   // 2 KB
    __shared__ _Float16 xvB[2][4][4][4][8];   // 2 KB
    // per-instance input ring: slot s&15 = {u0,u1,u2,1} per col, filled 8 ahead
    __shared__ _Float16 urA[16][4][4];        // 512 B
    __shared__ _Float16 urB[16][4][4];        // 512 B
    __shared__ float    hxf[BT][HID + 4];     // final fp32 hx for out-projection

    const int tid  = threadIdx.x;
    const int w    = tid >> 6;        // wave 0..7
    const int lane = tid & 63;
    const int q    = lane >> 4;       // 0..3
    const int n    = lane & 15;
    const int bbase = blockIdx.x * BT;

    const int hi   = (n >> 3) & 1;
    const int b2   = (n >> 2) & 1;
    const int col  = n & 3;                          // lane's batch column (within instance)
    const int hrow = w * 16 + q * 4 + hi * 2 + b2;   // lane's hidden row (bijective)

    // ---- A fragments in registers, pre-scaled by log2e (2*log2e for g gate) ----
    // Element i of lane-group q at K-tile kt holds Wcat_scaled[m][kt*32+q*8+i];
    // B uses the identical slot->k convention, so any HW k-permutation cancels.
    half8 A[4][5];
    #pragma unroll
    for (int t = 0; t < 4; ++t) {
        const float scl = (t == 2) ? L2E2 : L2E;
        const int m = t * 128 + w * 16 + n;          // gate row
        const float* whr = W_hh + m * HID;
        #pragma unroll
        for (int kt = 0; kt < 4; ++kt) {
            half8 a;
            #pragma unroll
            for (int i = 0; i < 8; ++i) a[i] = (_Float16)(whr[kt * 32 + q * 8 + i] * scl);
            A[t][kt] = a;
        }
        half8 a4 = {0, 0, 0, 0, 0, 0, 0, 0};        // augmented K-tile (u-proj + bias)
        if (q == 0) {                                // slots k=128..131
            const float* wir = W_ih + m * 64;
            float wx = 0.f, wy = 0.f, wz = 0.f, bb = 0.f;
            for (int hh = 0; hh < 64; ++hh) {
                float wv = wir[hh];
                wx += wv * W_inp[hh * 3 + 0];
                wy += wv * W_inp[hh * 3 + 1];
                wz += wv * W_inp[hh * 3 + 2];
                bb += wv * b_inp[hh];
            }
            bb += b_ih[m] + b_hh[m];
            a4[0] = (_Float16)(wx * scl); a4[1] = (_Float16)(wy * scl);
            a4[2] = (_Float16)(wz * scl); a4[3] = (_Float16)(bb * scl);
        }
        A[t][4] = a4;
    }

    // ---- Loader lane mapping: 96 floats = 8 steps x 4 cols x 3 -----------------
    // wave 1 feeds urA (cols 0..3), wave 2 feeds urB (cols 4..7)
    const int  F0 = lane, F1 = lane + 64;
    const int  col0 = F0 / 24, rem0 = F0 % 24, slot0 = rem0 / 3, wi0 = rem0 % 3;
    const bool f1v = (F1 < 96);
    const int  col1 = f1v ? F1 / 24 : 0, rem1 = f1v ? F1 % 24 : 0;
    const int  slot1 = rem1 / 3, wi1 = rem1 % 3;
    const int  ldcolofs = (w == 2) ? 4 : 0;          // wave2 loads instance B's cols
    const float* up0 = inputs + (size_t)(bbase + ldcolofs + col0) * (SEQ * 3) + wi0;
    const float* up1 = inputs + (size_t)(bbase + ldcolofs + col1) * (SEQ * 3) + wi1;

    // ---- Init LDS --------------------------------------------------------------
    for (int i = tid; i < 2 * 4 * 4 * 4 * 8; i += 512) {
        ((_Float16*)xvA)[i] = (_Float16)0.f;
        ((_Float16*)xvB)[i] = (_Float16)0.f;
    }
    if (tid < 64) {     // bias lane of every ring slot, never clobbered after
        urA[tid >> 2][tid & 3][3] = (_Float16)1.f;
        urB[tid >> 2][tid & 3][3] = (_Float16)1.f;
    }
    __syncthreads();
    for (int idx = tid; idx < BT * HID; idx += 512) {
        int c = idx >> 7, h = idx & 127;
        float v = hx0[(bbase + c) * HID + h];
        if (c < 4) xvA[0][h >> 5][(h >> 3) & 3][c][h & 7]     = (_Float16)v;
        else       xvB[0][h >> 5][(h >> 3) & 3][c - 4][h & 7] = (_Float16)v;
    }
    if (w == 1) {       // ring slots 0..7 = steps 0..7
        urA[slot0][col0][wi0] = (_Float16)up0[slot0 * 3];
        if (f1v) urA[slot1][col1][wi1] = (_Float16)up1[slot1 * 3];
    } else if (w == 2) {
        urB[slot0][col0][wi0] = (_Float16)up0[slot0 * 3];
        if (f1v) urB[slot1][col1][wi1] = (_Float16)up1[slot1 * 3];
    }
    float cA = cx0[(bbase + col) * HID + hrow];
    float cB = cx0[(bbase + 4 + col) * HID + hrow];
    __syncthreads();

    const int kw = hrow >> 5, qw = (hrow >> 3) & 3, iw = hrow & 7;
    float pend0 = 0.f, pend1 = 0.f, hlA = 0.f, hlB = 0.f;

    // ---- Recurrent loop: ONE barrier per step covers both instances ------------
    for (int s = 0; s < SEQ; ++s) {
        _Float16 (*brA)[4][4][8] = xvA[s & 1];
        _Float16 (*bwA)[4][4][8] = xvA[(s + 1) & 1];
        _Float16 (*brB)[4][4][8] = xvB[s & 1];
        _Float16 (*bwB)[4][4][8] = xvB[(s + 1) & 1];

        // deep input prefetch: issue at s%8==0 (8 ahead), LDS-write at s%8==4
        if (w == 1 || w == 2) {
            _Float16 (*urW)[4][4] = (w == 1) ? urA : urB;
            if ((s & 7) == 0) {
                int st0 = s + 8 + slot0; st0 = st0 > SEQ - 1 ? SEQ - 1 : st0;
                pend0 = up0[st0 * 3];
                if (f1v) { int st1 = s + 8 + slot1; st1 = st1 > SEQ - 1 ? SEQ - 1 : st1;
                           pend1 = up1[st1 * 3]; }
            } else if ((s & 7) == 4) {
                urW[(s + 4 + slot0) & 15][col0][wi0] = (_Float16)pend0;
                if (f1v) urW[(s + 4 + slot1) & 15][col1][wi1] = (_Float16)pend1;
            }
        }

        // ---- B fragments for both instances (independent load streams) --------
        half8 BA[5], BB[5];
        #pragma unroll
        for (int kt = 0; kt < 4; ++kt) {
            BA[kt] = *reinterpret_cast<const half8*>(&brA[kt][q][col][0]);
            BB[kt] = *reinterpret_cast<const half8*>(&brB[kt][q][col][0]);
        }
        {
            half8 z = {0, 0, 0, 0, 0, 0, 0, 0};
            BA[4] = z; BB[4] = z;
            if (q == 0) {
                half4 uA = *reinterpret_cast<const half4*>(&urA[s & 15][col][0]);
                half4 uB = *reinterpret_cast<const half4*>(&urB[s & 15][col][0]);
                BA[4][0] = uA[0]; BA[4][1] = uA[1]; BA[4][2] = uA[2]; BA[4][3] = uA[3];
                BB[4][0] = uB[0]; BB[4][1] = uB[1]; BB[4][2] = uB[2]; BB[4][3] = uB[3];
            }
        }

        // ---- two independent MFMA chain sets: B's issue hides A's latency ------
        f32x4 aA[4], aB[4];
        #pragma unroll
        for (int t = 0; t < 4; ++t) {
            f32x4 a = {0.f, 0.f, 0.f, 0.f};
            #pragma unroll
            for (int kt = 0; kt < 5; ++kt)
                a = __builtin_amdgcn_mfma_f32_16x16x32_f16(A[t][kt], BA[kt], a, 0, 0, 0);
            aA[t] = a;
            f32x4 b = {0.f, 0.f, 0.f, 0.f};
            #pragma unroll
            for (int kt = 0; kt < 5; ++kt)
                b = __builtin_amdgcn_mfma_f32_16x16x32_f16(A[t][kt], BB[kt], b, 0, 0, 0);
            aB[t] = b;
        }

        // ---- epilogue A (overlaps with tail of B's MFMA chains) ----------------
        {
            float g4[4];
            #pragma unroll
            for (int t = 0; t < 4; ++t) {
                float ra = b2 ? aA[t][1] : aA[t][0];
                float rb = b2 ? aA[t][3] : aA[t][2];
                g4[t] = hi ? rb : ra;
            }
            float iv = sigm2(g4[0]), fv = sigm2(g4[1]);
            float gv = tanh2(g4[2]), ov = sigm2(g4[3]);
            cA = fv * cA + iv * gv;
            float h = ov * (1.f - 2.f * rcp_(1.f + exp2_(cA * L2E2)));
            hlA = h;
            bwA[kw][qw][col][iw] = (_Float16)h;
        }
        // ---- epilogue B --------------------------------------------------------
        {
            float g4[4];
            #pragma unroll
            for (int t = 0; t < 4; ++t) {
                float ra = b2 ? aB[t][1] : aB[t][0];
                float rb = b2 ? aB[t][3] : aB[t][2];
                g4[t] = hi ? rb : ra;
            }
            float iv = sigm2(g4[0]), fv = sigm2(g4[1]);
            float gv = tanh2(g4[2]), ov = sigm2(g4[3]);
            cB = fv * cB + iv * gv;
            float h = ov * (1.f - 2.f * rcp_(1.f + exp2_(cB * L2E2)));
            hlB = h;
            bwB[kw][qw][col][iw] = (_Float16)h;
        }
        __syncthreads();
    }

    // ---- Out projection: out[b] = W_out @ hx_last + b_out ----------------------
    hxf[col][hrow]     = hlA;
    hxf[col + 4][hrow] = hlB;
    __syncthreads();
    if (tid < BT * 40) {
        int bl = tid / 40, o = tid % 40;
        const float* wr = W_out + o * HID;
        float a = b_out[o];
        #pragma unroll 8
        for (int k = 0; k < HID; ++k) a += wr[k] * hxf[bl][k];
        out[(bbase + bl) * 40 + o] = a;
    }
}

extern "C" void kernel_launch(void* const* d_in, const int* in_sizes, int n_in,
                              void* d_out, int out_size, void* d_ws, size_t ws_size,
                              hipStream_t stream) {
    const float* inputs = (const float*)d_in[0];
    const float* hx0    = (const float*)d_in[1];
    const float* cx0    = (const float*)d_in[2];
    const float* W_inp  = (const float*)d_in[3];
    const float* b_inp  = (const float*)d_in[4];
    const float* W_ih   = (const float*)d_in[5];
    const float* b_ih   = (const float*)d_in[6];
    const float* W_hh   = (const float*)d_in[7];
    const float* b_hh   = (const float*)d_in[8];
    const float* W_out  = (const float*)d_in[9];
    const float* b_out  = (const float*)d_in[10];
    float* out = (float*)d_out;

    lstm_mfma<<<NBLK, 512, 0, stream>>>(inputs, hx0, cx0, W_inp, b_inp, W_ih, b_ih,
                                        W_hh, b_hh, W_out, b_out, out);
}

// Round 7
// 2108.477 us; speedup vs baseline: 2.0950x; 2.0950x over previous
//
#include <hip/hip_runtime.h>

#define SEQ  4096
#define HID  128
#define BT   4            // real batch columns per block (replicated into 16 MFMA cols)
#define NBLK (256 / BT)   // 64 blocks

typedef _Float16 half8 __attribute__((ext_vector_type(8)));
typedef _Float16 half4 __attribute__((ext_vector_type(4)));
typedef float    f32x4 __attribute__((ext_vector_type(4)));

#define L2E  1.44269504088896340736f   // log2(e)
#define L2E2 2.88539008177792681472f   // 2*log2(e)

__device__ __forceinline__ float exp2_(float x) { return __builtin_amdgcn_exp2f(x); }
__device__ __forceinline__ float rcp_(float x)  { return __builtin_amdgcn_rcpf(x); }
// gate pre-scaled by log2e: sigmoid(x) = 1/(1+2^-x')
__device__ __forceinline__ float sigm2(float xp) { return rcp_(1.f + exp2_(-xp)); }
// gate pre-scaled by 2*log2e: tanh(x) = 1 - 2/(1+2^x')
__device__ __forceinline__ float tanh2(float xp) { return 1.f - 2.f * rcp_(1.f + exp2_(xp)); }

// One block = 4 batch elements, 8 waves. Wave w owns gate M-tiles {w,w+8,w+16,w+24}
// (all four gates for hidden rows [16w,16w+16)). B operand replicated over the 4
// column groups (col = n&3): lane-local epilogue (proven rounds 4-6).
// Input projection: 16 VALU FMAs per lane issued UNDER the MFMA-pipe occupancy
// (independent of MFMA results), added to the selected acc in the epilogue.
__global__ __launch_bounds__(512, 2)
void lstm_mfma(const float* __restrict__ inputs,   // (B,S,3)
               const float* __restrict__ hx0,      // (B,128)
               const float* __restrict__ cx0,      // (B,128)
               const float* __restrict__ W_inp,    // (64,3)
               const float* __restrict__ b_inp,    // (64)
               const float* __restrict__ W_ih,     // (512,64)
               const float* __restrict__ b_ih,     // (512)
               const float* __restrict__ W_hh,     // (512,128)
               const float* __restrict__ b_hh,     // (512)
               const float* __restrict__ W_out,    // (40,128)
               const float* __restrict__ b_out,    // (40)
               float*       __restrict__ out)      // (B,40)
{
    // h state, double-buffered, transposed: element (kt,q,c,i) = h[k=kt*32+q*8+i][col c]
    __shared__ _Float16 xvT[2][4][4][4][8];   // 2 KB
    // input ring: slot s&15 holds {u0,u1,u2,1} per col (filled 8 steps ahead)
    __shared__ _Float16 uring[16][4][4];      // 512 B
    __shared__ float    hxf[BT][HID + 4];     // final fp32 hx for out-projection

    const int tid  = threadIdx.x;
    const int w    = tid >> 6;        // wave 0..7
    const int lane = tid & 63;
    const int q    = lane >> 4;       // 0..3
    const int n    = lane & 15;
    const int bbase = blockIdx.x * BT;

    const int hi   = (n >> 3) & 1;
    const int b2   = (n >> 2) & 1;
    const int col  = n & 3;                          // lane's batch column
    const int hrow = w * 16 + q * 4 + hi * 2 + b2;   // lane's hidden row (bijective)

    // ---- A fragments in registers, pre-scaled by log2e (2*log2e for g gate) ----
    // Element i of lane-group q at K-tile kt holds Whh_scaled[m][kt*32+q*8+i];
    // B uses the identical slot->k convention, so any HW k-permutation cancels.
    half8 A[4][4];
    #pragma unroll
    for (int t = 0; t < 4; ++t) {
        const float scl = (t == 2) ? L2E2 : L2E;
        const int m = t * 128 + w * 16 + n;          // gate row
        const float* whr = W_hh + m * HID;
        #pragma unroll
        for (int kt = 0; kt < 4; ++kt) {
            half8 a;
            #pragma unroll
            for (int i = 0; i < 8; ++i) a[i] = (_Float16)(whr[kt * 32 + q * 8 + i] * scl);
            A[t][kt] = a;
        }
    }

    // ---- weff for THIS lane's epilogue row only (4 gates x {wx,wy,wz,beff}) -----
    float4 wf[4];
    #pragma unroll
    for (int t = 0; t < 4; ++t) {
        const float scl = (t == 2) ? L2E2 : L2E;
        const int m2 = t * 128 + hrow;
        const float* wir = W_ih + m2 * 64;
        float wx = 0.f, wy = 0.f, wz = 0.f, bb = 0.f;
        for (int hh = 0; hh < 64; ++hh) {
            float wv = wir[hh];
            wx += wv * W_inp[hh * 3 + 0];
            wy += wv * W_inp[hh * 3 + 1];
            wz += wv * W_inp[hh * 3 + 2];
            bb += wv * b_inp[hh];
        }
        bb += b_ih[m2] + b_hh[m2];
        wf[t] = make_float4(wx * scl, wy * scl, wz * scl, bb * scl);
    }

    // ---- Loader lane mapping (wave 1): 96 floats = 8 steps x 4 cols x 3 --------
    const int  F0 = lane, F1 = lane + 64;
    const int  col0 = F0 / 24, rem0 = F0 % 24, slot0 = rem0 / 3, wi0 = rem0 % 3;
    const bool f1v = (F1 < 96);
    const int  col1 = f1v ? F1 / 24 : 0, rem1 = f1v ? F1 % 24 : 0;
    const int  slot1 = rem1 / 3, wi1 = rem1 % 3;
    const float* up0 = inputs + (size_t)(bbase + col0) * (SEQ * 3) + wi0;
    const float* up1 = inputs + (size_t)(bbase + col1) * (SEQ * 3) + wi1;

    // ---- Init LDS --------------------------------------------------------------
    for (int i = tid; i < 2 * 4 * 4 * 4 * 8; i += 512) ((_Float16*)xvT)[i] = (_Float16)0.f;
    if (tid < 64) uring[tid >> 2][tid & 3][3] = (_Float16)1.f;
    __syncthreads();
    for (int idx = tid; idx < BT * HID; idx += 512) {
        int c = idx >> 7, h = idx & 127;
        xvT[0][h >> 5][(h >> 3) & 3][c][h & 7] = (_Float16)hx0[(bbase + c) * HID + h];
    }
    if (w == 1) {   // ring slots 0..7 = steps 0..7
        uring[slot0][col0][wi0] = (_Float16)up0[slot0 * 3];
        if (f1v) uring[slot1][col1][wi1] = (_Float16)up1[slot1 * 3];
    }
    float creg = cx0[(bbase + col) * HID + hrow];
    __syncthreads();

    const int kw = hrow >> 5, qw = (hrow >> 3) & 3, iw = hrow & 7;
    float pend0 = 0.f, pend1 = 0.f, hl = 0.f;

    // ---- Recurrent loop: 1 barrier per step ------------------------------------
    for (int s = 0; s < SEQ; ++s) {
        _Float16 (*br)[4][4][8] = xvT[s & 1];
        _Float16 (*bw)[4][4][8] = xvT[(s + 1) & 1];

        // deep input prefetch: issue at s%8==0 (8 ahead), LDS-write at s%8==4
        if (w == 1) {
            if ((s & 7) == 0) {
                int st0 = s + 8 + slot0; st0 = st0 > SEQ - 1 ? SEQ - 1 : st0;
                pend0 = up0[st0 * 3];
                if (f1v) { int st1 = s + 8 + slot1; st1 = st1 > SEQ - 1 ? SEQ - 1 : st1;
                           pend1 = up1[st1 * 3]; }
            } else if ((s & 7) == 4) {
                uring[(s + 4 + slot0) & 15][col0][wi0] = (_Float16)pend0;
                if (f1v) uring[(s + 4 + slot1) & 15][col1][wi1] = (_Float16)pend1;
            }
        }

        // B fragments + u: all 5 LDS reads issued back-to-back (broadcast, no conflict)
        half8 B[4];
        #pragma unroll
        for (int kt = 0; kt < 4; ++kt)
            B[kt] = *reinterpret_cast<const half8*>(&br[kt][q][col][0]);
        half4 u4 = *reinterpret_cast<const half4*>(&uring[s & 15][col][0]);

        // gates_hh = Whh_scaled @ h : 4 independent 4-deep MFMA chains
        __builtin_amdgcn_s_setprio(1);
        f32x4 acc[4];
        #pragma unroll
        for (int t = 0; t < 4; ++t) {
            f32x4 a = {0.f, 0.f, 0.f, 0.f};
            #pragma unroll
            for (int kt = 0; kt < 4; ++kt)
                a = __builtin_amdgcn_mfma_f32_16x16x32_f16(A[t][kt], B[kt], a, 0, 0, 0);
            acc[t] = a;
        }
        __builtin_amdgcn_s_setprio(0);

        // input projection for this lane's row: independent of MFMA results ->
        // issues on the VALU while the matrix pipe drains.
        const float u0 = (float)u4[0], u1 = (float)u4[1], u2 = (float)u4[2];
        float inp[4];
        #pragma unroll
        for (int t = 0; t < 4; ++t)
            inp[t] = fmaf(wf[t].x, u0, fmaf(wf[t].y, u1, fmaf(wf[t].z, u2, wf[t].w)));

        // lane-local row select (row r = 2*hi + b2) + input add
        float g4[4];
        #pragma unroll
        for (int t = 0; t < 4; ++t) {
            float ra = b2 ? acc[t][1] : acc[t][0];
            float rb = b2 ? acc[t][3] : acc[t][2];
            g4[t] = (hi ? rb : ra) + inp[t];
        }

        // one LSTM update per lane (fp32 state); all exp are exp2, no pre-muls
        float iv = sigm2(g4[0]), fv = sigm2(g4[1]);
        float gv = tanh2(g4[2]), ov = sigm2(g4[3]);
        creg = fv * creg + iv * gv;
        float h = ov * (1.f - 2.f * rcp_(1.f + exp2_(creg * L2E2)));
        hl = h;

        bw[kw][qw][col][iw] = (_Float16)h;   // 512 lanes cover all 128 rows x 4 cols
        __syncthreads();
    }

    // ---- Out projection: out[b] = W_out @ hx_last + b_out ----------------------
    hxf[col][hrow] = hl;
    __syncthreads();
    if (tid < BT * 40) {
        int bl = tid / 40, o = tid % 40;
        const float* wr = W_out + o * HID;
        float a = b_out[o];
        #pragma unroll 8
        for (int k = 0; k < HID; ++k) a += wr[k] * hxf[bl][k];
        out[(bbase + bl) * 40 + o] = a;
    }
}

extern "C" void kernel_launch(void* const* d_in, const int* in_sizes, int n_in,
                              void* d_out, int out_size, void* d_ws, size_t ws_size,
                              hipStream_t stream) {
    const float* inputs = (const float*)d_in[0];
    const float* hx0    = (const float*)d_in[1];
    const float* cx0    = (const float*)d_in[2];
    const float* W_inp  = (const float*)d_in[3];
    const float* b_inp  = (const float*)d_in[4];
    const float* W_ih   = (const float*)d_in[5];
    const float* b_ih   = (const float*)d_in[6];
    const float* W_hh   = (const float*)d_in[7];
    const float* b_hh   = (const float*)d_in[8];
    const float* W_out  = (const float*)d_in[9];
    const float* b_out  = (const float*)d_in[10];
    float* out = (float*)d_out;

    lstm_mfma<<<NBLK, 512, 0, stream>>>(inputs, hx0, cx0, W_inp, b_inp, W_ih, b_ih,
                                        W_hh, b_hh, W_out, b_out, out);
}

// Round 8
// 1786.719 us; speedup vs baseline: 2.4723x; 1.1801x over previous
//
#include <hip/hip_runtime.h>

#define SEQ  4096
#define HID  128
#define BT   4            // real batch columns per block (replicated into 16 MFMA cols)
#define NBLK (256 / BT)   // 64 blocks

typedef _Float16 half8 __attribute__((ext_vector_type(8)));
typedef float    f32x4 __attribute__((ext_vector_type(4)));

#define L2E  1.44269504088896340736f   // log2(e)
#define L2E2 2.88539008177792681472f   // 2*log2(e)

__device__ __forceinline__ float exp2_(float x) { return __builtin_amdgcn_exp2f(x); }
__device__ __forceinline__ float rcp_(float x)  { return __builtin_amdgcn_rcpf(x); }
// gate pre-scaled by log2e: sigmoid(x) = 1/(1+2^-x')
__device__ __forceinline__ float sigm2(float xp) { return rcp_(1.f + exp2_(-xp)); }
// gate pre-scaled by 2*log2e: tanh(x) = 1 - 2/(1+2^x')
__device__ __forceinline__ float tanh2(float xp) { return 1.f - 2.f * rcp_(1.f + exp2_(xp)); }

// One block = 4 batch elements, 8 waves. Wave w owns gate M-tiles {w,w+8,w+16,w+24}.
// B operand replicated over the 4 column groups (col = n&3): lane-local epilogue.
// Round 8: 16-step static unroll -> all LDS addresses are base+immediate, no
// per-step address/index VALU; uring holds f32 (no unpack cvts).
__global__ __launch_bounds__(512, 2)
void lstm_mfma(const float* __restrict__ inputs,   // (B,S,3)
               const float* __restrict__ hx0,      // (B,128)
               const float* __restrict__ cx0,      // (B,128)
               const float* __restrict__ W_inp,    // (64,3)
               const float* __restrict__ b_inp,    // (64)
               const float* __restrict__ W_ih,     // (512,64)
               const float* __restrict__ b_ih,     // (512)
               const float* __restrict__ W_hh,     // (512,128)
               const float* __restrict__ b_hh,     // (512)
               const float* __restrict__ W_out,    // (40,128)
               const float* __restrict__ b_out,    // (40)
               float*       __restrict__ out)      // (B,40)
{
    // h state, double-buffered, transposed: element (kt,q,c,i) = h[k=kt*32+q*8+i][col c]
    __shared__ _Float16 xvT[2][4][4][4][8];   // 2 KB
    // input ring (f32): slot s&15 holds {u0,u1,u2,pad} per col, filled 8+ steps ahead
    __shared__ float    uring[16][4][4];      // 4 KB
    __shared__ float    hxf[BT][HID + 4];     // final fp32 hx for out-projection

    const int tid  = threadIdx.x;
    const int w    = tid >> 6;        // wave 0..7
    const int lane = tid & 63;
    const int q    = lane >> 4;       // 0..3
    const int n    = lane & 15;
    const int bbase = blockIdx.x * BT;

    const int hi   = (n >> 3) & 1;
    const int b2   = (n >> 2) & 1;
    const int col  = n & 3;                          // lane's batch column
    const int hrow = w * 16 + q * 4 + hi * 2 + b2;   // lane's hidden row (bijective)

    // ---- A fragments in registers, pre-scaled by log2e (2*log2e for g gate) ----
    // Element i of lane-group q at K-tile kt holds Whh_scaled[m][kt*32+q*8+i];
    // B uses the identical slot->k convention, so any HW k-permutation cancels.
    half8 A[4][4];
    #pragma unroll
    for (int t = 0; t < 4; ++t) {
        const float scl = (t == 2) ? L2E2 : L2E;
        const int m = t * 128 + w * 16 + n;          // gate row
        const float* whr = W_hh + m * HID;
        #pragma unroll
        for (int kt = 0; kt < 4; ++kt) {
            half8 a;
            #pragma unroll
            for (int i = 0; i < 8; ++i) a[i] = (_Float16)(whr[kt * 32 + q * 8 + i] * scl);
            A[t][kt] = a;
        }
    }

    // ---- weff for THIS lane's epilogue row only (4 gates x {wx,wy,wz,beff}) -----
    float4 wf[4];
    #pragma unroll
    for (int t = 0; t < 4; ++t) {
        const float scl = (t == 2) ? L2E2 : L2E;
        const int m2 = t * 128 + hrow;
        const float* wir = W_ih + m2 * 64;
        float wx = 0.f, wy = 0.f, wz = 0.f, bb = 0.f;
        for (int hh = 0; hh < 64; ++hh) {
            float wv = wir[hh];
            wx += wv * W_inp[hh * 3 + 0];
            wy += wv * W_inp[hh * 3 + 1];
            wz += wv * W_inp[hh * 3 + 2];
            bb += wv * b_inp[hh];
        }
        bb += b_ih[m2] + b_hh[m2];
        wf[t] = make_float4(wx * scl, wy * scl, wz * scl, bb * scl);
    }

    // ---- Loader lane mapping (wave 1): 96 floats = 8 steps x 4 cols x 3 --------
    const int  F0 = lane, F1 = lane + 64;
    const int  col0 = F0 / 24, rem0 = F0 % 24, slot0 = rem0 / 3, wi0 = rem0 % 3;
    const bool f1v = (F1 < 96);
    const int  col1 = f1v ? F1 / 24 : 0, rem1 = f1v ? F1 % 24 : 0;
    const int  slot1 = rem1 / 3, wi1 = rem1 % 3;
    const float* up0 = inputs + (size_t)(bbase + col0) * (SEQ * 3) + wi0;
    const float* up1 = inputs + (size_t)(bbase + col1) * (SEQ * 3) + wi1;

    // ---- Init LDS --------------------------------------------------------------
    for (int i = tid; i < 2 * 4 * 4 * 4 * 8; i += 512) ((_Float16*)xvT)[i] = (_Float16)0.f;
    __syncthreads();
    for (int idx = tid; idx < BT * HID; idx += 512) {
        int c = idx >> 7, h = idx & 127;
        xvT[0][h >> 5][(h >> 3) & 3][c][h & 7] = (_Float16)hx0[(bbase + c) * HID + h];
    }
    if (w == 1) {   // ring slots 0..15 = steps 0..15
        uring[slot0][col0][wi0]     = up0[slot0 * 3];
        uring[8 + slot0][col0][wi0] = up0[(8 + slot0) * 3];
        if (f1v) {
            uring[slot1][col1][wi1]     = up1[slot1 * 3];
            uring[8 + slot1][col1][wi1] = up1[(8 + slot1) * 3];
        }
    }
    float creg = cx0[(bbase + col) * HID + hrow];
    __syncthreads();

    const int kw = hrow >> 5, qw = (hrow >> 3) & 3, iw = hrow & 7;
    float pend0 = 0.f, pend1 = 0.f, hl = 0.f;

    // ---- Recurrent loop: 16 statically-unrolled substeps per iteration ---------
    for (int sb = 0; sb < SEQ; sb += 16) {
        #pragma unroll
        for (int j = 0; j < 16; ++j) {
            // (sb + j) & 15 == j   and   (sb + j) & 1 == j & 1  (sb % 16 == 0)
            _Float16 (*br)[4][4][8] = xvT[j & 1];
            _Float16 (*bw)[4][4][8] = xvT[(j + 1) & 1];

            // deep input prefetch (wave 1): issue at j=0/8, LDS-write at j=4/12
            if (w == 1) {
                if (j == 0) {
                    int st0 = sb + 8 + slot0; if (st0 > SEQ - 1) st0 = SEQ - 1;
                    pend0 = up0[st0 * 3];
                    if (f1v) { int st1 = sb + 8 + slot1; if (st1 > SEQ - 1) st1 = SEQ - 1;
                               pend1 = up1[st1 * 3]; }
                } else if (j == 4) {        // slots 8..15 <- steps sb+8..sb+15
                    uring[8 + slot0][col0][wi0] = pend0;
                    if (f1v) uring[8 + slot1][col1][wi1] = pend1;
                } else if (j == 8) {
                    int st0 = sb + 16 + slot0; if (st0 > SEQ - 1) st0 = SEQ - 1;
                    pend0 = up0[st0 * 3];
                    if (f1v) { int st1 = sb + 16 + slot1; if (st1 > SEQ - 1) st1 = SEQ - 1;
                               pend1 = up1[st1 * 3]; }
                } else if (j == 12) {       // slots 0..7 <- steps sb+16..sb+23
                    uring[slot0][col0][wi0] = pend0;
                    if (f1v) uring[slot1][col1][wi1] = pend1;
                }
            }

            // u (f32x4 broadcast read, static slot) + B fragments (static offsets)
            const f32x4 u4 = *reinterpret_cast<const f32x4*>(&uring[j][col][0]);
            const half8 B0 = *reinterpret_cast<const half8*>(&br[0][q][col][0]);
            const half8 B1 = *reinterpret_cast<const half8*>(&br[1][q][col][0]);
            const half8 B2 = *reinterpret_cast<const half8*>(&br[2][q][col][0]);
            const half8 B3 = *reinterpret_cast<const half8*>(&br[3][q][col][0]);

            // gates_hh = Whh_scaled @ h : 4 independent 4-deep MFMA chains
            __builtin_amdgcn_s_setprio(1);
            f32x4 acc[4];
            #pragma unroll
            for (int t = 0; t < 4; ++t) {
                f32x4 a = {0.f, 0.f, 0.f, 0.f};
                a = __builtin_amdgcn_mfma_f32_16x16x32_f16(A[t][0], B0, a, 0, 0, 0);
                a = __builtin_amdgcn_mfma_f32_16x16x32_f16(A[t][1], B1, a, 0, 0, 0);
                a = __builtin_amdgcn_mfma_f32_16x16x32_f16(A[t][2], B2, a, 0, 0, 0);
                a = __builtin_amdgcn_mfma_f32_16x16x32_f16(A[t][3], B3, a, 0, 0, 0);
                acc[t] = a;
            }
            __builtin_amdgcn_s_setprio(0);

            // input projection for this lane's row (off the MFMA critical path)
            float inp[4];
            #pragma unroll
            for (int t = 0; t < 4; ++t)
                inp[t] = fmaf(wf[t].x, u4[0], fmaf(wf[t].y, u4[1],
                         fmaf(wf[t].z, u4[2], wf[t].w)));

            // lane-local row select (row r = 2*hi + b2) + input add
            float g4[4];
            #pragma unroll
            for (int t = 0; t < 4; ++t) {
                float ra = b2 ? acc[t][1] : acc[t][0];
                float rb = b2 ? acc[t][3] : acc[t][2];
                g4[t] = (hi ? rb : ra) + inp[t];
            }

            // one LSTM update per lane (fp32 state); all exp are exp2
            float iv = sigm2(g4[0]), fv = sigm2(g4[1]);
            float gv = tanh2(g4[2]), ov = sigm2(g4[3]);
            creg = fv * creg + iv * gv;
            float h = ov * (1.f - 2.f * rcp_(1.f + exp2_(creg * L2E2)));
            hl = h;

            bw[kw][qw][col][iw] = (_Float16)h;   // 512 lanes cover 128 rows x 4 cols
            __syncthreads();
        }
    }

    // ---- Out projection: out[b] = W_out @ hx_last + b_out ----------------------
    hxf[col][hrow] = hl;
    __syncthreads();
    if (tid < BT * 40) {
        int bl = tid / 40, o = tid % 40;
        const float* wr = W_out + o * HID;
        float a = b_out[o];
        #pragma unroll 8
        for (int k = 0; k < HID; ++k) a += wr[k] * hxf[bl][k];
        out[(bbase + bl) * 40 + o] = a;
    }
}

extern "C" void kernel_launch(void* const* d_in, const int* in_sizes, int n_in,
                              void* d_out, int out_size, void* d_ws, size_t ws_size,
                              hipStream_t stream) {
    const float* inputs = (const float*)d_in[0];
    const float* hx0    = (const float*)d_in[1];
    const float* cx0    = (const float*)d_in[2];
    const float* W_inp  = (const float*)d_in[3];
    const float* b_inp  = (const float*)d_in[4];
    const float* W_ih   = (const float*)d_in[5];
    const float* b_ih   = (const float*)d_in[6];
    const float* W_hh   = (const float*)d_in[7];
    const float* b_hh   = (const float*)d_in[8];
    const float* W_out  = (const float*)d_in[9];
    const float* b_out  = (const float*)d_in[10];
    float* out = (float*)d_out;

    lstm_mfma<<<NBLK, 512, 0, stream>>>(inputs, hx0, cx0, W_inp, b_inp, W_ih, b_ih,
                                        W_hh, b_hh, W_out, b_out, out);
}

// Round 9
// 1683.689 us; speedup vs baseline: 2.6236x; 1.0612x over previous
//
#include <hip/hip_runtime.h>

#define SEQ  4096
#define HID  128
#define BT   4            // real batch columns per block (replicated into 16 MFMA cols)
#define NBLK (256 / BT)   // 64 blocks

typedef int   i32x4 __attribute__((ext_vector_type(4)));
typedef float f32x4 __attribute__((ext_vector_type(4)));

#define L2E  1.44269504088896340736f   // log2(e)
#define L2E2 2.88539008177792681472f   // 2*log2(e)

__device__ __forceinline__ float exp2_(float x) { return __builtin_amdgcn_exp2f(x); }
__device__ __forceinline__ float rcp_(float x)  { return __builtin_amdgcn_rcpf(x); }
// gate pre-scaled by log2e: sigmoid(x) = 1/(1+2^-x')
__device__ __forceinline__ float sigm2(float xp) { return rcp_(1.f + exp2_(-xp)); }
// gate pre-scaled by 2*log2e: tanh(x) = 1 - 2/(1+2^x')
__device__ __forceinline__ float tanh2(float xp) { return 1.f - 2.f * rcp_(1.f + exp2_(xp)); }

// One block = 4 batch elements, 8 waves. Wave w owns gate M-tiles {w,w+8,w+16,w+24}.
// B operand replicated over the 4 column groups (col = n&3): lane-local epilogue.
// Round 9: recurrent GEMM in int8 (mfma_i32_16x16x64_i8, K=64 -> 2 K-tiles):
// halves MFMA issue (the measured dominant cost). W per-row scales; h quantized
// at fixed 1/127 (|h|<1). MFMA is exact int math; input proj + state stay f32.
// t-serial chains with interleaved per-gate activations shrink the serial tail.
__global__ __launch_bounds__(512, 2)
void lstm_mfma(const float* __restrict__ inputs,   // (B,S,3)
               const float* __restrict__ hx0,      // (B,128)
               const float* __restrict__ cx0,      // (B,128)
               const float* __restrict__ W_inp,    // (64,3)
               const float* __restrict__ b_inp,    // (64)
               const float* __restrict__ W_ih,     // (512,64)
               const float* __restrict__ b_ih,     // (512)
               const float* __restrict__ W_hh,     // (512,128)
               const float* __restrict__ b_hh,     // (512)
               const float* __restrict__ W_out,    // (40,128)
               const float* __restrict__ b_out,    // (40)
               float*       __restrict__ out)      // (B,40)
{
    // h state (int8), double-buffered, transposed:
    // byte (kt,q,c,i) = h_q[k = kt*64 + q*16 + i][col c]   -> 1 KB total
    __shared__ signed char xvT[2][2][4][4][16];
    // input ring (f32): slot s&15 holds {u0,u1,u2,pad} per col, filled 8+ ahead
    __shared__ float uring[16][4][4];      // 4 KB
    __shared__ float hxf[BT][HID + 4];     // final fp32 hx for out-projection

    const int tid  = threadIdx.x;
    const int w    = tid >> 6;        // wave 0..7
    const int lane = tid & 63;
    const int q    = lane >> 4;       // 0..3
    const int n    = lane & 15;
    const int bbase = blockIdx.x * BT;

    const int hi   = (n >> 3) & 1;
    const int b2   = (n >> 2) & 1;
    const int col  = n & 3;                          // lane's batch column
    const int hrow = w * 16 + q * 4 + hi * 2 + b2;   // lane's hidden row (bijective)

    // ---- A fragments: int8, per-row symmetric scale -----------------------------
    // Lane (q,n), tile t, K-tile kt holds W_hh[m][kt*64 + q*16 + i] quantized.
    // A and B use the identical slot->k convention, so any HW k-permutation cancels
    // (same bijection argument as the f16 kernels, rounds 2-8).
    i32x4 A[4][2];
    float dq[4];                          // dequant scale for THIS lane's epilogue row
    #pragma unroll
    for (int t = 0; t < 4; ++t) {
        const int m = t * 128 + w * 16 + n;
        const float* whr = W_hh + m * HID;
        float mx = 0.f;
        for (int k = 0; k < 128; ++k) mx = fmaxf(mx, fabsf(whr[k]));
        const float rs = (mx > 0.f) ? 127.f / mx : 0.f;
        #pragma unroll
        for (int kt = 0; kt < 2; ++kt) {
            union { signed char c[16]; i32x4 v; } pk;
            #pragma unroll
            for (int i = 0; i < 16; ++i)
                pk.c[i] = (signed char)(int)rintf(whr[kt * 64 + q * 16 + i] * rs);
            A[t][kt] = pk.v;
        }
        // epilogue row me = t*128 + hrow: scale recomputed identically by every
        // lane that touches row me (deterministic fp -> consistent quantization)
        const int me = t * 128 + hrow;
        const float* whe = W_hh + me * HID;
        float mxe = 0.f;
        for (int k = 0; k < 128; ++k) mxe = fmaxf(mxe, fabsf(whe[k]));
        dq[t] = (mxe / 127.f) * (1.f / 127.f) * ((t == 2) ? L2E2 : L2E);
    }

    // ---- weff for THIS lane's epilogue row (input proj, exact f32, L2E-scaled) --
    float4 wf[4];
    #pragma unroll
    for (int t = 0; t < 4; ++t) {
        const float scl = (t == 2) ? L2E2 : L2E;
        const int m2 = t * 128 + hrow;
        const float* wir = W_ih + m2 * 64;
        float wx = 0.f, wy = 0.f, wz = 0.f, bb = 0.f;
        for (int hh = 0; hh < 64; ++hh) {
            float wv = wir[hh];
            wx += wv * W_inp[hh * 3 + 0];
            wy += wv * W_inp[hh * 3 + 1];
            wz += wv * W_inp[hh * 3 + 2];
            bb += wv * b_inp[hh];
        }
        bb += b_ih[m2] + b_hh[m2];
        wf[t] = make_float4(wx * scl, wy * scl, wz * scl, bb * scl);
    }

    // ---- Loader lane mapping (wave 1): 96 floats = 8 steps x 4 cols x 3 --------
    const int  F0 = lane, F1 = lane + 64;
    const int  col0 = F0 / 24, rem0 = F0 % 24, slot0 = rem0 / 3, wi0 = rem0 % 3;
    const bool f1v = (F1 < 96);
    const int  col1 = f1v ? F1 / 24 : 0, rem1 = f1v ? F1 % 24 : 0;
    const int  slot1 = rem1 / 3, wi1 = rem1 % 3;
    const float* up0 = inputs + (size_t)(bbase + col0) * (SEQ * 3) + wi0;
    const float* up1 = inputs + (size_t)(bbase + col1) * (SEQ * 3) + wi1;

    // ---- Init LDS --------------------------------------------------------------
    for (int i = tid; i < 2 * 2 * 4 * 4 * 16; i += 512) ((signed char*)xvT)[i] = 0;
    __syncthreads();
    for (int idx = tid; idx < BT * HID; idx += 512) {
        int c = idx >> 7, h = idx & 127;
        float v = hx0[(bbase + c) * HID + h];
        v = fminf(fmaxf(v, -1.f), 1.f);   // clip: only affects step 1, fully damped
        xvT[0][h >> 6][(h >> 4) & 3][c][h & 15] = (signed char)(int)rintf(v * 127.f);
    }
    if (w == 1) {   // ring slots 0..15 = steps 0..15
        uring[slot0][col0][wi0]     = up0[slot0 * 3];
        uring[8 + slot0][col0][wi0] = up0[(8 + slot0) * 3];
        if (f1v) {
            uring[slot1][col1][wi1]     = up1[slot1 * 3];
            uring[8 + slot1][col1][wi1] = up1[(8 + slot1) * 3];
        }
    }
    float creg = cx0[(bbase + col) * HID + hrow];
    __syncthreads();

    const int kw = hrow >> 6, qw = (hrow >> 4) & 3, iw = hrow & 15;
    float pend0 = 0.f, pend1 = 0.f, hl = 0.f;

    // ---- Recurrent loop: 16 statically-unrolled substeps per iteration ---------
    for (int sb = 0; sb < SEQ; sb += 16) {
        #pragma unroll
        for (int j = 0; j < 16; ++j) {
            signed char (*br)[4][4][16] = xvT[j & 1];
            signed char (*bw)[4][4][16] = xvT[(j + 1) & 1];

            // deep input prefetch (wave 1): issue at j=0/8, LDS-write at j=4/12
            if (w == 1) {
                if (j == 0) {
                    int st0 = sb + 8 + slot0; if (st0 > SEQ - 1) st0 = SEQ - 1;
                    pend0 = up0[st0 * 3];
                    if (f1v) { int st1 = sb + 8 + slot1; if (st1 > SEQ - 1) st1 = SEQ - 1;
                               pend1 = up1[st1 * 3]; }
                } else if (j == 4) {        // slots 8..15 <- steps sb+8..sb+15
                    uring[8 + slot0][col0][wi0] = pend0;
                    if (f1v) uring[8 + slot1][col1][wi1] = pend1;
                } else if (j == 8) {
                    int st0 = sb + 16 + slot0; if (st0 > SEQ - 1) st0 = SEQ - 1;
                    pend0 = up0[st0 * 3];
                    if (f1v) { int st1 = sb + 16 + slot1; if (st1 > SEQ - 1) st1 = SEQ - 1;
                               pend1 = up1[st1 * 3]; }
                } else if (j == 12) {       // slots 0..7 <- steps sb+16..sb+23
                    uring[slot0][col0][wi0] = pend0;
                    if (f1v) uring[slot1][col1][wi1] = pend1;
                }
            }

            // u (f32x4 broadcast, static slot) + int8 B fragments (static offsets)
            const f32x4 u4 = *reinterpret_cast<const f32x4*>(&uring[j][col][0]);
            const i32x4 B0 = *reinterpret_cast<const i32x4*>(&br[0][q][col][0]);
            const i32x4 B1 = *reinterpret_cast<const i32x4*>(&br[1][q][col][0]);

            // input projection (exact f32, off the MFMA critical path)
            float inp0 = fmaf(wf[0].x, u4[0], fmaf(wf[0].y, u4[1], fmaf(wf[0].z, u4[2], wf[0].w)));
            float inp1 = fmaf(wf[1].x, u4[0], fmaf(wf[1].y, u4[1], fmaf(wf[1].z, u4[2], wf[1].w)));
            float inp2 = fmaf(wf[2].x, u4[0], fmaf(wf[2].y, u4[1], fmaf(wf[2].z, u4[2], wf[2].w)));
            float inp3 = fmaf(wf[3].x, u4[0], fmaf(wf[3].y, u4[1], fmaf(wf[3].z, u4[2], wf[3].w)));

            const i32x4 z4 = {0, 0, 0, 0};
            __builtin_amdgcn_s_setprio(1);
            // t-serial chains; per-gate activation interleaves under later chains
            i32x4 a0 = __builtin_amdgcn_mfma_i32_16x16x64_i8(A[0][0], B0, z4, 0, 0, 0);
            a0       = __builtin_amdgcn_mfma_i32_16x16x64_i8(A[0][1], B1, a0, 0, 0, 0);
            int r0 = hi ? (b2 ? a0[3] : a0[2]) : (b2 ? a0[1] : a0[0]);
            float iv = sigm2((float)r0 * dq[0] + inp0);

            i32x4 a1 = __builtin_amdgcn_mfma_i32_16x16x64_i8(A[1][0], B0, z4, 0, 0, 0);
            a1       = __builtin_amdgcn_mfma_i32_16x16x64_i8(A[1][1], B1, a1, 0, 0, 0);
            int r1 = hi ? (b2 ? a1[3] : a1[2]) : (b2 ? a1[1] : a1[0]);
            float fv = sigm2((float)r1 * dq[1] + inp1);

            i32x4 a2 = __builtin_amdgcn_mfma_i32_16x16x64_i8(A[2][0], B0, z4, 0, 0, 0);
            a2       = __builtin_amdgcn_mfma_i32_16x16x64_i8(A[2][1], B1, a2, 0, 0, 0);
            int r2 = hi ? (b2 ? a2[3] : a2[2]) : (b2 ? a2[1] : a2[0]);
            float gv = tanh2((float)r2 * dq[2] + inp2);
            creg = fv * creg + iv * gv;                   // c-update hides under t3
            float th = tanh2(creg * L2E2);

            i32x4 a3 = __builtin_amdgcn_mfma_i32_16x16x64_i8(A[3][0], B0, z4, 0, 0, 0);
            a3       = __builtin_amdgcn_mfma_i32_16x16x64_i8(A[3][1], B1, a3, 0, 0, 0);
            __builtin_amdgcn_s_setprio(0);
            int r3 = hi ? (b2 ? a3[3] : a3[2]) : (b2 ? a3[1] : a3[0]);
            float ov = sigm2((float)r3 * dq[3] + inp3);

            float h = ov * th;                            // |h| < 1 by construction
            hl = h;
            bw[kw][qw][col][iw] = (signed char)(int)rintf(h * 127.f);
            __syncthreads();
        }
    }

    // ---- Out projection: out[b] = W_out @ hx_last + b_out (f32 h, unquantized) --
    hxf[col][hrow] = hl;
    __syncthreads();
    if (tid < BT * 40) {
        int bl = tid / 40, o = tid % 40;
        const float* wr = W_out + o * HID;
        float a = b_out[o];
        #pragma unroll 8
        for (int k = 0; k < HID; ++k) a += wr[k] * hxf[bl][k];
        out[(bbase + bl) * 40 + o] = a;
    }
}

extern "C" void kernel_launch(void* const* d_in, const int* in_sizes, int n_in,
                              void* d_out, int out_size, void* d_ws, size_t ws_size,
                              hipStream_t stream) {
    const float* inputs = (const float*)d_in[0];
    const float* hx0    = (const float*)d_in[1];
    const float* cx0    = (const float*)d_in[2];
    const float* W_inp  = (const float*)d_in[3];
    const float* b_inp  = (const float*)d_in[4];
    const float* W_ih   = (const float*)d_in[5];
    const float* b_ih   = (const float*)d_in[6];
    const float* W_hh   = (const float*)d_in[7];
    const float* b_hh   = (const float*)d_in[8];
    const float* W_out  = (const float*)d_in[9];
    const float* b_out  = (const float*)d_in[10];
    float* out = (float*)d_out;

    lstm_mfma<<<NBLK, 512, 0, stream>>>(inputs, hx0, cx0, W_inp, b_inp, W_ih, b_ih,
                                        W_hh, b_hh, W_out, b_out, out);
}

// Round 10
// 1461.443 us; speedup vs baseline: 3.0226x; 1.1521x over previous
//
#include <hip/hip_runtime.h>

#define SEQ  4096
#define HID  128
#define BT   2            // real batch columns per block (replicated into 16 MFMA cols)
#define NBLK (256 / BT)   // 128 blocks, 256 threads each -> 1 wave per SIMD

typedef int   i32x4 __attribute__((ext_vector_type(4)));
typedef float f32x4 __attribute__((ext_vector_type(4)));

#define L2E  1.44269504088896340736f   // log2(e)
#define L2E2 2.88539008177792681472f   // 2*log2(e)

__device__ __forceinline__ float exp2_(float x) { return __builtin_amdgcn_exp2f(x); }
__device__ __forceinline__ float rcp_(float x)  { return __builtin_amdgcn_rcpf(x); }
// gate pre-scaled by log2e: sigmoid(x) = 1/(1+2^-x')
__device__ __forceinline__ float sigm2(float xp) { return rcp_(1.f + exp2_(-xp)); }
// gate pre-scaled by 2*log2e: tanh(x) = 1 - 2/(1+2^x')
__device__ __forceinline__ float tanh2(float xp) { return 1.f - 2.f * rcp_(1.f + exp2_(xp)); }

// One block = 2 batch columns, 4 waves (256 thr) -> ONE wave per SIMD: the
// lockstep 2nd wave of rounds 4-9 added only pipe contention (zero latency
// hiding across a barrier), so removing it halves per-SIMD VALU/TRANS issue
// at identical per-SIMD MFMA issue (wave now owns 8 M-tiles = 16 i8 MFMAs).
// Wave w owns M-tiles {t*8+w, t*8+w+4} (gate t rows 16w.. and 16w+64..).
// B replicated 8-way over column groups (col = n&1): lane-local epilogue,
// each lane does exactly ONE LSTM update.
__global__ __launch_bounds__(256, 2)
void lstm_mfma(const float* __restrict__ inputs,   // (B,S,3)
               const float* __restrict__ hx0,      // (B,128)
               const float* __restrict__ cx0,      // (B,128)
               const float* __restrict__ W_inp,    // (64,3)
               const float* __restrict__ b_inp,    // (64)
               const float* __restrict__ W_ih,     // (512,64)
               const float* __restrict__ b_ih,     // (512)
               const float* __restrict__ W_hh,     // (512,128)
               const float* __restrict__ b_hh,     // (512)
               const float* __restrict__ W_out,    // (40,128)
               const float* __restrict__ b_out,    // (40)
               float*       __restrict__ out)      // (B,40)
{
    // h state (int8), double-buffered, transposed:
    // byte (kt,q,c,i) = h_q[k = kt*64 + q*16 + i][col c]
    __shared__ signed char xvT[2][2][4][2][16];   // 512 B
    // input ring (f32): slot s&15 holds {u0,u1,u2,pad} per col, filled 8+ ahead
    __shared__ float uring[16][2][4];             // 512 B
    __shared__ float hxf[BT][HID + 4];            // final fp32 hx for out-projection

    const int tid  = threadIdx.x;
    const int w    = tid >> 6;        // wave 0..3 (one per SIMD)
    const int lane = tid & 63;
    const int q    = lane >> 4;       // 0..3
    const int n    = lane & 15;
    const int bbase = blockIdx.x * BT;

    const int  cc   = n & 1;                 // lane's batch column
    const bool rb1  = (n >> 1) & 1;          // acc reg select bit 0
    const bool rb2  = (n >> 2) & 1;          // acc reg select bit 1
    const bool hi8  = (n >> 3) & 1;          // M-subtile select
    const int  rr   = (n >> 1) & 3;
    const int  hrow = w * 16 + (hi8 ? 64 : 0) + q * 4 + rr;  // lane's hidden row

    // ---- A fragments: int8, per-row symmetric scale, 2 M-subtiles per gate ------
    // Lane (q,n), gate t, subtile s, K-tile kt holds W_hh[m][kt*64 + q*16 + i],
    // m = t*128 + (w + 4s)*16 + n. A and B share the slot->k bijection (verified).
    i32x4 A[4][2][2];
    float dq[4];                          // dequant scale for THIS lane's epilogue row
    #pragma unroll
    for (int t = 0; t < 4; ++t) {
        #pragma unroll
        for (int s = 0; s < 2; ++s) {
            const int m = t * 128 + (w + 4 * s) * 16 + n;
            const float* whr = W_hh + m * HID;
            float mx = 0.f;
            for (int k = 0; k < 128; ++k) mx = fmaxf(mx, fabsf(whr[k]));
            const float rs = (mx > 0.f) ? 127.f / mx : 0.f;
            #pragma unroll
            for (int kt = 0; kt < 2; ++kt) {
                union { signed char c[16]; i32x4 v; } pk;
                #pragma unroll
                for (int i = 0; i < 16; ++i)
                    pk.c[i] = (signed char)(int)rintf(whr[kt * 64 + q * 16 + i] * rs);
                A[t][s][kt] = pk.v;
            }
        }
        // epilogue row me = t*128 + hrow: recomputed identically by every lane
        // that touches row me (deterministic fp -> consistent with A-quant above)
        const int me = t * 128 + hrow;
        const float* whe = W_hh + me * HID;
        float mxe = 0.f;
        for (int k = 0; k < 128; ++k) mxe = fmaxf(mxe, fabsf(whe[k]));
        dq[t] = (mxe / 127.f) * (1.f / 127.f) * ((t == 2) ? L2E2 : L2E);
    }

    // ---- weff for THIS lane's epilogue row (input proj, exact f32, L2E-scaled) --
    float4 wf[4];
    #pragma unroll
    for (int t = 0; t < 4; ++t) {
        const float scl = (t == 2) ? L2E2 : L2E;
        const int m2 = t * 128 + hrow;
        const float* wir = W_ih + m2 * 64;
        float wx = 0.f, wy = 0.f, wz = 0.f, bb = 0.f;
        for (int hh = 0; hh < 64; ++hh) {
            float wv = wir[hh];
            wx += wv * W_inp[hh * 3 + 0];
            wy += wv * W_inp[hh * 3 + 1];
            wz += wv * W_inp[hh * 3 + 2];
            bb += wv * b_inp[hh];
        }
        bb += b_ih[m2] + b_hh[m2];
        wf[t] = make_float4(wx * scl, wy * scl, wz * scl, bb * scl);
    }

    // ---- Loader lane mapping (wave 1): 48 floats = 8 steps x 2 cols x 3 ---------
    const bool uldr = (w == 1) && (lane < 48);
    const int  col0 = lane / 24, rem0 = lane % 24, slot0 = rem0 / 3, wi0 = rem0 % 3;
    const float* up0 = inputs + (size_t)(bbase + col0) * (SEQ * 3) + wi0;

    // ---- Init LDS ----------------------------------------------------------------
    if (tid < 2 * 2 * 4 * 2 * 16 / 4) ((int*)xvT)[tid] = 0;
    __syncthreads();
    {   // h0 quantized (clip to [-1,1]: only perturbs step 1, damped by forget gate)
        int c = tid >> 7, h = tid & 127;
        float v = hx0[(bbase + c) * HID + h];
        v = fminf(fmaxf(v, -1.f), 1.f);
        xvT[0][h >> 6][(h >> 4) & 3][c][h & 15] = (signed char)(int)rintf(v * 127.f);
    }
    if (uldr) {   // ring slots 0..15 = steps 0..15
        uring[slot0][col0][wi0]     = up0[slot0 * 3];
        uring[8 + slot0][col0][wi0] = up0[(8 + slot0) * 3];
    }
    float creg = cx0[(bbase + cc) * HID + hrow];
    __syncthreads();

    float pend0 = 0.f, hl = 0.f;

    // ---- Recurrent loop: 16 statically-unrolled substeps per iteration -----------
    for (int sb = 0; sb < SEQ; sb += 16) {
        #pragma unroll
        for (int j = 0; j < 16; ++j) {
            signed char (*br)[4][2][16] = xvT[j & 1];
            signed char (*bw)[4][2][16] = xvT[(j + 1) & 1];

            // deep input prefetch: issue at j=0/8 (8+ steps ahead), write at j=4/12
            if (uldr) {
                if (j == 0) {
                    int st0 = sb + 8 + slot0; if (st0 > SEQ - 1) st0 = SEQ - 1;
                    pend0 = up0[st0 * 3];
                } else if (j == 4) {        // slots 8..15 <- steps sb+8..sb+15
                    uring[8 + slot0][col0][wi0] = pend0;
                } else if (j == 8) {
                    int st0 = sb + 16 + slot0; if (st0 > SEQ - 1) st0 = SEQ - 1;
                    pend0 = up0[st0 * 3];
                } else if (j == 12) {       // slots 0..7 <- steps sb+16..sb+23
                    uring[slot0][col0][wi0] = pend0;
                }
            }

            // u (f32x4 broadcast, static slot) + int8 B fragments (static offsets)
            const f32x4 u4 = *reinterpret_cast<const f32x4*>(&uring[j][cc][0]);
            const i32x4 B0 = *reinterpret_cast<const i32x4*>(&br[0][q][cc][0]);
            const i32x4 B1 = *reinterpret_cast<const i32x4*>(&br[1][q][cc][0]);

            // input projection (exact f32, independent of MFMA results)
            float inp[4];
            #pragma unroll
            for (int t = 0; t < 4; ++t)
                inp[t] = fmaf(wf[t].x, u4[0], fmaf(wf[t].y, u4[1],
                         fmaf(wf[t].z, u4[2], wf[t].w)));

            const i32x4 z4 = {0, 0, 0, 0};
            // per-gate: 4 MFMAs (2 subtiles x 2 K) then 1-of-8 select + activation;
            // activation VALU/TRANS hides under the next gate's MFMA drain.
            float gv4[4];
            #pragma unroll
            for (int t = 0; t < 4; ++t) {
                i32x4 a0 = __builtin_amdgcn_mfma_i32_16x16x64_i8(A[t][0][0], B0, z4, 0, 0, 0);
                a0       = __builtin_amdgcn_mfma_i32_16x16x64_i8(A[t][0][1], B1, a0, 0, 0, 0);
                i32x4 a1 = __builtin_amdgcn_mfma_i32_16x16x64_i8(A[t][1][0], B0, z4, 0, 0, 0);
                a1       = __builtin_amdgcn_mfma_i32_16x16x64_i8(A[t][1][1], B1, a1, 0, 0, 0);
                int s0 = rb1 ? a0[1] : a0[0];
                int s1 = rb1 ? a0[3] : a0[2];
                int v0 = rb2 ? s1 : s0;
                int t0 = rb1 ? a1[1] : a1[0];
                int t1 = rb1 ? a1[3] : a1[2];
                int v1 = rb2 ? t1 : t0;
                int v  = hi8 ? v1 : v0;
                gv4[t] = (float)v * dq[t] + inp[t];
            }

            // one LSTM update per lane (fp32 state); all exp are exp2
            float iv = sigm2(gv4[0]), fv = sigm2(gv4[1]);
            float gg = tanh2(gv4[2]), ov = sigm2(gv4[3]);
            creg = fv * creg + iv * gg;
            float th = tanh2(creg * L2E2);
            float h  = ov * th;                       // |h| < 1 by construction
            hl = h;

            bw[hi8 ? 1 : 0][w][cc][q * 4 + rr] = (signed char)(int)rintf(h * 127.f);
            __syncthreads();
        }
    }

    // ---- Out projection: out[b] = W_out @ hx_last + b_out (f32 h, unquantized) ---
    hxf[cc][hrow] = hl;
    __syncthreads();
    if (tid < BT * 40) {
        int bl = tid / 40, o = tid % 40;
        const float* wr = W_out + o * HID;
        float a = b_out[o];
        #pragma unroll 8
        for (int k = 0; k < HID; ++k) a += wr[k] * hxf[bl][k];
        out[(bbase + bl) * 40 + o] = a;
    }
}

extern "C" void kernel_launch(void* const* d_in, const int* in_sizes, int n_in,
                              void* d_out, int out_size, void* d_ws, size_t ws_size,
                              hipStream_t stream) {
    const float* inputs = (const float*)d_in[0];
    const float* hx0    = (const float*)d_in[1];
    const float* cx0    = (const float*)d_in[2];
    const float* W_inp  = (const float*)d_in[3];
    const float* b_inp  = (const float*)d_in[4];
    const float* W_ih   = (const float*)d_in[5];
    const float* b_ih   = (const float*)d_in[6];
    const float* W_hh   = (const float*)d_in[7];
    const float* b_hh   = (const float*)d_in[8];
    const float* W_out  = (const float*)d_in[9];
    const float* b_out  = (const float*)d_in[10];
    float* out = (float*)d_out;

    lstm_mfma<<<NBLK, 256, 0, stream>>>(inputs, hx0, cx0, W_inp, b_inp, W_ih, b_ih,
                                        W_hh, b_hh, W_out, b_out, out);
}